// Round 6
// baseline (6753.066 us; speedup 1.0000x reference)
//
#include <hip/hip_runtime.h>
#include <hip/hip_cooperative_groups.h>
#include <cstdint>

namespace cg = cooperative_groups;

using u16 = unsigned short;
using u32 = uint32_t;

typedef __bf16 bf16x8 __attribute__((ext_vector_type(8)));
typedef float  f32x4  __attribute__((ext_vector_type(4)));

typedef const __attribute__((address_space(1))) void GV;
typedef __attribute__((address_space(3))) void LV;

#define MFMA(a, b, c) __builtin_amdgcn_mfma_f32_16x16x32_bf16((a), (b), (c), 0, 0, 0)

static __device__ __forceinline__ void gl_lds16(const u16* g, u16* l) {
  __builtin_amdgcn_global_load_lds((GV*)g, (LV*)l, 16, 0, 0);
}

// wait until the oldest in-flight stage (4 loads) has landed; ring lead = 2.
#define RING_WAIT(rem) do {                                                \
    if ((rem) >= 3)      asm volatile("s_waitcnt vmcnt(8)" ::: "memory");  \
    else if ((rem) == 2) asm volatile("s_waitcnt vmcnt(4)" ::: "memory");  \
    else                 asm volatile("s_waitcnt vmcnt(0)" ::: "memory");  \
  } while (0)

// ---------------- numeric helpers ----------------
static __device__ __forceinline__ u16 f2bf(float x) {
  u32 u = __float_as_uint(x);
  u32 r = (u + 0x7FFFu + ((u >> 16) & 1u)) >> 16;   // RNE
  return (u16)r;
}

static __device__ __forceinline__ u32 rotl32(u32 v, int s) {
  return (v << s) | (v >> (32 - s));
}

// JAX threefry2x32 (20 rounds)
static __device__ __forceinline__ void threefry2x32(u32 k0, u32 k1, u32 x0, u32 x1,
                                                    u32& o0, u32& o1) {
  u32 k2 = k0 ^ k1 ^ 0x1BD11BDAu;
  x0 += k0; x1 += k1;
  x0 += x1; x1 = rotl32(x1, 13); x1 ^= x0;
  x0 += x1; x1 = rotl32(x1, 15); x1 ^= x0;
  x0 += x1; x1 = rotl32(x1, 26); x1 ^= x0;
  x0 += x1; x1 = rotl32(x1, 6);  x1 ^= x0;
  x0 += k1; x1 += k2 + 1u;
  x0 += x1; x1 = rotl32(x1, 17); x1 ^= x0;
  x0 += x1; x1 = rotl32(x1, 29); x1 ^= x0;
  x0 += x1; x1 = rotl32(x1, 16); x1 ^= x0;
  x0 += x1; x1 = rotl32(x1, 24); x1 ^= x0;
  x0 += k2; x1 += k0 + 2u;
  x0 += x1; x1 = rotl32(x1, 13); x1 ^= x0;
  x0 += x1; x1 = rotl32(x1, 15); x1 ^= x0;
  x0 += x1; x1 = rotl32(x1, 26); x1 ^= x0;
  x0 += x1; x1 = rotl32(x1, 6);  x1 ^= x0;
  x0 += k0; x1 += k1 + 3u;
  x0 += x1; x1 = rotl32(x1, 17); x1 ^= x0;
  x0 += x1; x1 = rotl32(x1, 29); x1 ^= x0;
  x0 += x1; x1 = rotl32(x1, 16); x1 ^= x0;
  x0 += x1; x1 = rotl32(x1, 24); x1 ^= x0;
  x0 += k1; x1 += k2 + 4u;
  x0 += x1; x1 = rotl32(x1, 13); x1 ^= x0;
  x0 += x1; x1 = rotl32(x1, 15); x1 ^= x0;
  x0 += x1; x1 = rotl32(x1, 26); x1 ^= x0;
  x0 += x1; x1 = rotl32(x1, 6);  x1 ^= x0;
  x0 += k2; x1 += k0 + 5u;
  o0 = x0; o1 = x1;
}

// bits -> N(0,1) exactly like jax.random.normal(f32)
static __device__ __forceinline__ float bits_to_normal(u32 bits) {
  const float lo = __uint_as_float(0xBF7FFFFFu);
  float f = __uint_as_float((bits >> 9) | 0x3F800000u) - 1.0f;
  float x = fmaxf(lo, f * 2.0f + lo);
  float w = -logf((1.0f - x) * (1.0f + x));
  float p;
  if (w < 5.0f) {
    w -= 2.5f;
    p = 2.81022636e-08f;
    p = fmaf(p, w, 3.43273939e-07f);
    p = fmaf(p, w, -3.5233877e-06f);
    p = fmaf(p, w, -4.39150654e-06f);
    p = fmaf(p, w, 0.00021858087f);
    p = fmaf(p, w, -0.00125372503f);
    p = fmaf(p, w, -0.00417768164f);
    p = fmaf(p, w, 0.246640727f);
    p = fmaf(p, w, 1.50140941f);
  } else {
    w = sqrtf(w) - 3.0f;
    p = -0.000200214257f;
    p = fmaf(p, w, 0.000100950558f);
    p = fmaf(p, w, 0.00134934322f);
    p = fmaf(p, w, -0.00367342844f);
    p = fmaf(p, w, 0.00573950773f);
    p = fmaf(p, w, -0.0076224613f);
    p = fmaf(p, w, 0.00943887047f);
    p = fmaf(p, w, 1.00167406f);
    p = fmaf(p, w, 2.83297682f);
  }
  return 1.41421356f * p * x;
}

// ---------------- S1: pack weights (transpose + f32->bf16) ----------------
// W1 (4097,1024) -> W1T (1024 cols, 4096 k) bf16; W2 (1024,4096) -> W2T (4096, 1024)
__global__ __launch_bounds__(256) void s1_pack(
    const float* __restrict__ W1f, const float* __restrict__ W1g,
    const float* __restrict__ W2f, const float* __restrict__ W2g,
    u16* __restrict__ W1fT, u16* __restrict__ W1gT,
    u16* __restrict__ W2fT, u16* __restrict__ W2gT) {
  __shared__ float tile[64][65];
  const int z = blockIdx.z;
  const float* in = (z == 0) ? W1f : (z == 1) ? W1g : (z == 2) ? W2f : W2g;
  u16* out = (z == 0) ? W1fT : (z == 1) ? W1gT : (z == 2) ? W2fT : W2gT;
  const int R = (z < 2) ? 4096 : 1024;
  const int C = (z < 2) ? 1024 : 4096;
  const int rt = (z < 2) ? blockIdx.x : blockIdx.y;
  const int ct = (z < 2) ? blockIdx.y : blockIdx.x;
  const int r0 = rt * 64, c0 = ct * 64;
  const int tix = threadIdx.x;
  #pragma unroll
  for (int i = 0; i < 16; ++i) {
    int lin = i * 256 + tix;
    int row = lin >> 6, col = lin & 63;
    tile[row][col] = in[(size_t)(r0 + row) * C + c0 + col];
  }
  __syncthreads();
  #pragma unroll
  for (int i = 0; i < 16; ++i) {
    int lin = i * 256 + tix;
    int orow = lin >> 6, ocol = lin & 63;
    out[(size_t)(c0 + orow) * R + r0 + ocol] = f2bf(tile[ocol][orow]);
  }
}

// ---------------- persistent SDE kernel ----------------
// 256 blocks x 512 threads, cooperative. Per step:
//   phase A (blocks<128): H[64, my 16 cols of f||g] = tanh(Abf @ W1 + c)
//     waves = 4 m-frags x 2 K-halves, per-wave barrier-free LDS ring.
//   grid.sync
//   phase B (all 256): C = H @ W2 (f and g via net-waves) -> SDE update -> A/Abf/out
//   grid.sync
__global__ __launch_bounds__(512) void sde_persist(
    const float* __restrict__ A0, const float* __restrict__ tarr,
    const u16* __restrict__ W1fT, const u16* __restrict__ W1gT,
    const u16* __restrict__ W2fT, const u16* __restrict__ W2gT,
    const float* __restrict__ b1f, const float* __restrict__ b1g,
    const float* __restrict__ W1fv, const float* __restrict__ W1gv,
    const float* __restrict__ b2f, const float* __restrict__ b2g,
    float* __restrict__ A, u16* __restrict__ Abf,
    u16* __restrict__ Hf, u16* __restrict__ Hg,
    float* __restrict__ out) {
  cg::grid_group grid = cg::this_grid();
  __shared__ __align__(16) u16 smem[65536];   // 128 KB: 8 waves x (A,B) x 4 bufs x 2KB
  const int bid = blockIdx.x, tix = threadIdx.x;
  const int wid = tix >> 6, lane = tix & 63;
  const int lr = lane & 15, kg = lane >> 4;
  const int m = wid & 3, hi = wid >> 2;       // m-frag; K-half (A) / net (B)
  const int wm = m * 16;
  u16* ringA = smem + wid * 8192;
  u16* ringB = ringA + 4096;
  const int srow = lane >> 3, sch = lane & 7;          // staging row/chunk per lane
  const int ssw = (sch ^ (srow & 7)) * 8;              // pre-swizzled source chunk
  const u32 rdswz = (u32)((lr & 7) << 4);

  // ---- init: A, Abf, t=0 output ----
  #pragma unroll
  for (int q = 0; q < 2; ++q) {
    const int e = q * 131072 + bid * 512 + tix;
    const float a0 = A0[e];
    A[e] = a0;
    Abf[e] = f2bf(a0);
    const int n = e & 4095, b = e >> 12;
    const float sig = (n % 65 == 0) ? 0.0f : 1.0f / (1.0f + expf(-a0));
    #pragma unroll
    for (int s = 0; s < 4; ++s)
      out[((size_t)(s * 64) * 64 + b) * 4096 + n] = sig;
  }
  grid.sync();

  const float dt = tarr[1] - tarr[0];
  const float sdt = sqrtf(dt);

  for (int step = 0; step < 63; ++step) {
    // ================= phase A =================
    if (bid < 128) {
      const int cb = bid * 16;
      const int fg = cb >> 10, cbase = cb & 1023;
      const u16* __restrict__ WT = fg ? W1gT : W1fT;
      const int kbase = hi * 2048;

      auto stageA = [&](int it) {
        const int buf = it & 3;
        u16* dA = ringA + buf * 1024;
        u16* dB = ringB + buf * 1024;
        const int kb = kbase + it * 64;
        #pragma unroll
        for (int c = 0; c < 2; ++c) {
          const int row = c * 8 + srow;
          const int sw = (sch ^ (row & 7)) * 8;
          gl_lds16(Abf + (size_t)(wm + row) * 4096 + kb + sw, dA + c * 512);
          gl_lds16(WT + (size_t)(cbase + row) * 4096 + kb + sw, dB + c * 512);
        }
      };
      stageA(0); stageA(1); stageA(2);

      f32x4 acc = {0.f, 0.f, 0.f, 0.f};
      #pragma unroll
      for (int it = 0; it < 32; ++it) {
        RING_WAIT(32 - it);
        const int buf = it & 3;
        const char* cA = (const char*)(ringA + buf * 1024);
        const char* cB = (const char*)(ringB + buf * 1024);
        const u32 o0 = (u32)lr * 128 + (((u32)(kg * 16)) ^ rdswz);
        const u32 o1 = (u32)lr * 128 + (((u32)(64 + kg * 16)) ^ rdswz);
        bf16x8 a0 = *(const bf16x8*)(cA + o0);
        bf16x8 b0 = *(const bf16x8*)(cB + o0);
        bf16x8 a1 = *(const bf16x8*)(cA + o1);
        bf16x8 b1 = *(const bf16x8*)(cB + o1);
        if (it + 3 < 32) stageA(it + 3);
        acc = MFMA(a0, b0, acc);
        acc = MFMA(a1, b1, acc);
      }

      // K-half exchange + tanh + H write
      __syncthreads();
      float* ex = (float*)smem;
      if (hi == 1) *(f32x4*)(ex + ((m * 64 + lane) << 2)) = acc;
      __syncthreads();
      if (hi == 0) {
        f32x4 tot = acc + *(const f32x4*)(ex + ((m * 64 + lane) << 2));
        const int nc = cbase + lr;
        const float* __restrict__ b1v = fg ? b1g : b1f;
        const float* __restrict__ wl = (fg ? W1gv : W1fv) + (size_t)4096 * 1024;
        const float cc = b1v[nc] + tarr[step] * wl[nc];
        u16* __restrict__ H = fg ? Hg : Hf;
        const int rb = wm + kg * 4;
        #pragma unroll
        for (int r = 0; r < 4; ++r)
          H[(size_t)(rb + r) * 1024 + nc] = f2bf(tanhf(tot[r] + cc));
      }
    }
    grid.sync();

    // ================= phase B =================
    {
      const int c0 = bid * 16;
      const u16* __restrict__ HA = hi ? Hg : Hf;
      const u16* __restrict__ W2T = hi ? W2gT : W2fT;

      auto stageB = [&](int it) {
        const int buf = it & 3;
        u16* dA = ringA + buf * 1024;
        u16* dB = ringB + buf * 1024;
        const int kb = it * 64;
        #pragma unroll
        for (int c = 0; c < 2; ++c) {
          const int row = c * 8 + srow;
          const int sw = (sch ^ (row & 7)) * 8;
          gl_lds16(HA + (size_t)(wm + row) * 1024 + kb + sw, dA + c * 512);
          gl_lds16(W2T + (size_t)(c0 + row) * 1024 + kb + sw, dB + c * 512);
        }
      };
      stageB(0); stageB(1); stageB(2);

      f32x4 acc = {0.f, 0.f, 0.f, 0.f};
      #pragma unroll
      for (int it = 0; it < 16; ++it) {
        RING_WAIT(16 - it);
        const int buf = it & 3;
        const char* cA = (const char*)(ringA + buf * 1024);
        const char* cB = (const char*)(ringB + buf * 1024);
        const u32 o0 = (u32)lr * 128 + (((u32)(kg * 16)) ^ rdswz);
        const u32 o1 = (u32)lr * 128 + (((u32)(64 + kg * 16)) ^ rdswz);
        bf16x8 a0 = *(const bf16x8*)(cA + o0);
        bf16x8 b0 = *(const bf16x8*)(cB + o0);
        bf16x8 a1 = *(const bf16x8*)(cA + o1);
        bf16x8 b1 = *(const bf16x8*)(cB + o1);
        if (it + 3 < 16) stageB(it + 3);
        acc = MFMA(a0, b0, acc);
        acc = MFMA(a1, b1, acc);
      }

      // net exchange + SDE update
      __syncthreads();
      float* ex = (float*)smem;
      *(f32x4*)(ex + ((wid * 64 + lane) << 2)) = acc;
      __syncthreads();
      if (hi == 0) {
        const f32x4 CF = acc;
        const f32x4 CG = *(const f32x4*)(ex + (((wid + 4) * 64 + lane) << 2));
        const int nc = c0 + lr;
        const float bfv = b2f[nc], bgv = b2g[nc];
        const int rb = wm + kg * 4;
        u32 k0s, k1s;
        threefry2x32(0u, 42u, 0u, (u32)step, k0s, k1s);
        #pragma unroll
        for (int r = 0; r < 4; ++r) {
          const int mg = rb + r;
          const float drift = CF[r] + bfv;
          const float graw = CG[r] + bgv;
          const float diff = fmaxf(graw, 0.0f) + log1pf(expf(-fabsf(graw)));
          const int e = mg * 4096 + nc;
          u32 y0, y1;
          threefry2x32(k0s, k1s, 0u, (u32)e, y0, y1);
          const float dw = bits_to_normal(y0 ^ y1) * sdt;
          const float anew = A[e] + drift * dt + diff * dw;
          A[e] = anew;
          Abf[e] = f2bf(anew);
          const float sig = (nc % 65 == 0) ? 0.0f : 1.0f / (1.0f + expf(-anew));
          #pragma unroll
          for (int s = 0; s < 4; ++s)
            out[((size_t)(s * 64 + step + 1) * 64 + mg) * 4096 + nc] = sig;
        }
      }
    }
    grid.sync();
  }
}

// ---------------- launch ----------------
extern "C" void kernel_launch(void* const* d_in, const int* in_sizes, int n_in,
                              void* d_out, int out_size, void* d_ws, size_t ws_size,
                              hipStream_t stream) {
  const float* A0 = (const float*)d_in[0];
  const float* tarr = (const float*)d_in[1];
  const float* W1f = (const float*)d_in[2];
  const float* b1f = (const float*)d_in[3];
  const float* W2f = (const float*)d_in[4];
  const float* b2f = (const float*)d_in[5];
  const float* W1g = (const float*)d_in[6];
  const float* b1g = (const float*)d_in[7];
  const float* W2g = (const float*)d_in[8];
  const float* b2g = (const float*)d_in[9];
  float* outp = (float*)d_out;
  char* ws = (char*)d_ws;
  const size_t MB = 1024 * 1024;
  u16* W1fT = (u16*)(ws + 0 * MB);
  u16* W1gT = (u16*)(ws + 8 * MB);
  u16* W2fT = (u16*)(ws + 16 * MB);
  u16* W2gT = (u16*)(ws + 24 * MB);
  float* A   = (float*)(ws + 32 * MB);            // 1 MB (64x4096 f32)
  u16* Abf   = (u16*)(ws + 33 * MB);              // 512 KB
  u16* Hf    = (u16*)(ws + 34 * MB);              // 128 KB
  u16* Hg    = (u16*)(ws + 34 * MB + 128 * 1024); // 128 KB

  s1_pack<<<dim3(64, 16, 4), 256, 0, stream>>>(W1f, W1g, W2f, W2g,
                                               W1fT, W1gT, W2fT, W2gT);

  void* kargs[] = {
    (void*)&A0, (void*)&tarr,
    (void*)&W1fT, (void*)&W1gT, (void*)&W2fT, (void*)&W2gT,
    (void*)&b1f, (void*)&b1g, (void*)&W1f, (void*)&W1g,
    (void*)&b2f, (void*)&b2g,
    (void*)&A, (void*)&Abf, (void*)&Hf, (void*)&Hg, (void*)&outp
  };
  hipLaunchCooperativeKernel((const void*)sde_persist, dim3(256), dim3(512),
                             kargs, 0, stream);
}

// Round 7
// 1110.969 us; speedup vs baseline: 6.0785x; 6.0785x over previous
//
#include <hip/hip_runtime.h>
#include <cstdint>

using u16 = unsigned short;
using u32 = uint32_t;

typedef __bf16 bf16x8 __attribute__((ext_vector_type(8)));
typedef float  f32x4  __attribute__((ext_vector_type(4)));
typedef u32    uvec4  __attribute__((ext_vector_type(4)));

#define MFMA(a, b, c) __builtin_amdgcn_mfma_f32_16x16x32_bf16((a), (b), (c), 0, 0, 0)

// ---------------- numeric helpers ----------------
static __device__ __forceinline__ u16 f2bf(float x) {
  u32 u = __float_as_uint(x);
  u32 r = (u + 0x7FFFu + ((u >> 16) & 1u)) >> 16;   // RNE
  return (u16)r;
}

static __device__ __forceinline__ u32 rotl32(u32 v, int s) {
  return (v << s) | (v >> (32 - s));
}

// JAX threefry2x32 (20 rounds)
static __device__ __forceinline__ void threefry2x32(u32 k0, u32 k1, u32 x0, u32 x1,
                                                    u32& o0, u32& o1) {
  u32 k2 = k0 ^ k1 ^ 0x1BD11BDAu;
  x0 += k0; x1 += k1;
  x0 += x1; x1 = rotl32(x1, 13); x1 ^= x0;
  x0 += x1; x1 = rotl32(x1, 15); x1 ^= x0;
  x0 += x1; x1 = rotl32(x1, 26); x1 ^= x0;
  x0 += x1; x1 = rotl32(x1, 6);  x1 ^= x0;
  x0 += k1; x1 += k2 + 1u;
  x0 += x1; x1 = rotl32(x1, 17); x1 ^= x0;
  x0 += x1; x1 = rotl32(x1, 29); x1 ^= x0;
  x0 += x1; x1 = rotl32(x1, 16); x1 ^= x0;
  x0 += x1; x1 = rotl32(x1, 24); x1 ^= x0;
  x0 += k2; x1 += k0 + 2u;
  x0 += x1; x1 = rotl32(x1, 13); x1 ^= x0;
  x0 += x1; x1 = rotl32(x1, 15); x1 ^= x0;
  x0 += x1; x1 = rotl32(x1, 26); x1 ^= x0;
  x0 += x1; x1 = rotl32(x1, 6);  x1 ^= x0;
  x0 += k0; x1 += k1 + 3u;
  x0 += x1; x1 = rotl32(x1, 17); x1 ^= x0;
  x0 += x1; x1 = rotl32(x1, 29); x1 ^= x0;
  x0 += x1; x1 = rotl32(x1, 16); x1 ^= x0;
  x0 += x1; x1 = rotl32(x1, 24); x1 ^= x0;
  x0 += k1; x1 += k2 + 4u;
  x0 += x1; x1 = rotl32(x1, 13); x1 ^= x0;
  x0 += x1; x1 = rotl32(x1, 15); x1 ^= x0;
  x0 += x1; x1 = rotl32(x1, 26); x1 ^= x0;
  x0 += x1; x1 = rotl32(x1, 6);  x1 ^= x0;
  x0 += k2; x1 += k0 + 5u;
  o0 = x0; o1 = x1;
}

// bits -> N(0,1) exactly like jax.random.normal(f32)
static __device__ __forceinline__ float bits_to_normal(u32 bits) {
  const float lo = __uint_as_float(0xBF7FFFFFu);
  float f = __uint_as_float((bits >> 9) | 0x3F800000u) - 1.0f;
  float x = fmaxf(lo, f * 2.0f + lo);
  float w = -logf((1.0f - x) * (1.0f + x));
  float p;
  if (w < 5.0f) {
    w -= 2.5f;
    p = 2.81022636e-08f;
    p = fmaf(p, w, 3.43273939e-07f);
    p = fmaf(p, w, -3.5233877e-06f);
    p = fmaf(p, w, -4.39150654e-06f);
    p = fmaf(p, w, 0.00021858087f);
    p = fmaf(p, w, -0.00125372503f);
    p = fmaf(p, w, -0.00417768164f);
    p = fmaf(p, w, 0.246640727f);
    p = fmaf(p, w, 1.50140941f);
  } else {
    w = sqrtf(w) - 3.0f;
    p = -0.000200214257f;
    p = fmaf(p, w, 0.000100950558f);
    p = fmaf(p, w, 0.00134934322f);
    p = fmaf(p, w, -0.00367342844f);
    p = fmaf(p, w, 0.00573950773f);
    p = fmaf(p, w, -0.0076224613f);
    p = fmaf(p, w, 0.00943887047f);
    p = fmaf(p, w, 1.00167406f);
    p = fmaf(p, w, 2.83297682f);
  }
  return 1.41421356f * p * x;
}

// ---------------- S1: fragment-pack weights directly from f32 ----------------
// W1P[net][ct 64][q 128]: frag 64 lanes x 16B; lane l = (col ct*16+(l&15), k q*32+(l>>4)*8)
// W2P[net][ct16 256][q 32]: same fragment rule against K=1024
__global__ __launch_bounds__(256) void s1_frag(
    const float* __restrict__ W1f, const float* __restrict__ W1g,
    const float* __restrict__ W2f, const float* __restrict__ W2g,
    u16* __restrict__ W1P, u16* __restrict__ W2P) {
  const int gid = blockIdx.x * 256 + threadIdx.x;
  const int f = gid >> 6, l = gid & 63;
  const int lr = l & 15, kg = l >> 4;
  u32 wbuf[4];
  if (f < 16384) {                       // W1P
    const int net = f >> 13, r = f & 8191, ct = r >> 7, q = r & 127;
    const float* __restrict__ src = net ? W1g : W1f;
    const int k = q * 32 + kg * 8, c = ct * 16 + lr;
    #pragma unroll
    for (int p = 0; p < 4; ++p) {
      u16 e0 = f2bf(src[(size_t)(k + 2 * p) * 1024 + c]);
      u16 e1 = f2bf(src[(size_t)(k + 2 * p + 1) * 1024 + c]);
      wbuf[p] = (u32)e0 | ((u32)e1 << 16);
    }
    *(uvec4*)(W1P + (size_t)f * 512 + l * 8) = *(uvec4*)wbuf;
  } else {                               // W2P
    const int f2 = f - 16384;
    const int net = f2 >> 13, r = f2 & 8191, ct = r >> 5, q = r & 31;
    const float* __restrict__ src = net ? W2g : W2f;
    const int k = q * 32 + kg * 8, c = ct * 16 + lr;
    #pragma unroll
    for (int p = 0; p < 4; ++p) {
      u16 e0 = f2bf(src[(size_t)(k + 2 * p) * 4096 + c]);
      u16 e1 = f2bf(src[(size_t)(k + 2 * p + 1) * 4096 + c]);
      wbuf[p] = (u32)e0 | ((u32)e1 << 16);
    }
    *(uvec4*)(W2P + (size_t)f2 * 512 + l * 8) = *(uvec4*)wbuf;
  }
}

// ---------------- S2: init A (f32), APack (frag bf16), t=0 output ----------------
__global__ __launch_bounds__(256) void s2_init(
    const float* __restrict__ A0, float* __restrict__ A, u16* __restrict__ APack,
    float* __restrict__ out) {
  const int gid = blockIdx.x * 256 + threadIdx.x;   // 262144
  const float a0 = A0[gid];
  A[gid] = a0;
  const int n = gid & 4095, b = gid >> 12;
  const float sig = (n % 65 == 0) ? 0.0f : 1.0f / (1.0f + expf(-a0));
  #pragma unroll
  for (int s = 0; s < 4; ++s)
    out[((size_t)(s * 64) * 64 + b) * 4096 + n] = sig;
  if (gid < 32768) {                     // APack: 512 frags [m 4][q 128]
    const int fr = gid >> 6, l = gid & 63;
    const int m = fr >> 7, q = fr & 127;
    const int row = m * 16 + (l & 15);
    const int k = q * 32 + (l >> 4) * 8;
    u32 wbuf[4];
    #pragma unroll
    for (int p = 0; p < 4; ++p) {
      u16 e0 = f2bf(A0[(size_t)row * 4096 + k + 2 * p]);
      u16 e1 = f2bf(A0[(size_t)row * 4096 + k + 2 * p + 1]);
      wbuf[p] = (u32)e0 | ((u32)e1 << 16);
    }
    *(uvec4*)(APack + (size_t)fr * 512 + l * 8) = *(uvec4*)wbuf;
  }
}

// ---------------- dW pregen ----------------
__global__ __launch_bounds__(256) void dw_gen(
    const float* __restrict__ tarr, float* __restrict__ dst_base, int step_param) {
  const int bid = blockIdx.x, tix = threadIdx.x;
  const int step = (step_param < 0) ? (bid >> 5) : step_param;
  const int sub = (step_param < 0) ? (bid & 31) : bid;
  u32 k0, k1;
  threefry2x32(0u, 42u, 0u, (u32)step, k0, k1);
  const float sdt = sqrtf(tarr[1] - tarr[0]);
  float* dst = dst_base + ((step_param < 0) ? (size_t)step * 262144 : 0);
  #pragma unroll
  for (int j = 0; j < 32; ++j) {
    u32 e = (u32)(sub * 8192 + j * 256 + tix);
    u32 y0, y1;
    threefry2x32(k0, k1, 0u, e, y0, y1);
    dst[e] = bits_to_normal(y0 ^ y1) * sdt;
  }
}

// ---------------- G1: HPack = frag(tanh(A @ W1 + b1 + t*w1last)) ----------------
// grid 256 = mp(2) x ctF(128 = net*64+ct). 8 waves = ks(4) x m(2). Wave: 16x16 frag,
// K=1024 quarter, 32 chunk-stream, no barriers in K-loop.
__global__ __launch_bounds__(512, 2) void g1_hidden(
    const u16* __restrict__ APack, const u16* __restrict__ W1P,
    u16* __restrict__ HPack,
    const float* __restrict__ b1f, const float* __restrict__ b1g,
    const float* __restrict__ W1fv, const float* __restrict__ W1gv,
    const float* __restrict__ tarr, int step) {
  __shared__ f32x4 ex[8][64];
  __shared__ __align__(16) u16 tileH[2][16][16];
  const int bid = blockIdx.x, tix = threadIdx.x;
  const int wid = tix >> 6, lane = tix & 63;
  const int mp = bid >> 7, ctF = bid & 127;
  const int net = ctF >> 6, ct = ctF & 63;
  const int m = wid & 1, ks = wid >> 1;
  const int mG = mp * 2 + m;
  const u16* pa = APack + ((size_t)(mG * 128 + ks * 32)) * 512 + lane * 8;
  const u16* pb = W1P + ((size_t)((net * 64 + ct) * 128 + ks * 32)) * 512 + lane * 8;

  bf16x8 av[8], bv[8];
  #pragma unroll
  for (int d = 0; d < 8; ++d) {
    av[d] = *(const bf16x8*)(pa + d * 512);
    bv[d] = *(const bf16x8*)(pb + d * 512);
  }
  f32x4 acc = {0.f, 0.f, 0.f, 0.f};
  #pragma unroll
  for (int j = 0; j < 32; ++j) {
    const int s = j & 7;
    acc = MFMA(av[s], bv[s], acc);
    if (j + 8 < 32) {
      av[s] = *(const bf16x8*)(pa + (j + 8) * 512);
      bv[s] = *(const bf16x8*)(pb + (j + 8) * 512);
    }
  }
  ex[wid][lane] = acc;
  __syncthreads();

  // distributed epilogue: wave -> (eM = wid&1, eR = wid>>1)
  {
    const int eM = wid & 1, eR = wid >> 1;
    const f32x4 s0 = ex[eM][lane];
    const f32x4 s1 = ex[2 + eM][lane];
    const f32x4 s2 = ex[4 + eM][lane];
    const f32x4 s3 = ex[6 + eM][lane];
    const float ch = s0[eR] + s1[eR] + s2[eR] + s3[eR];
    const int nc = ct * 16 + (lane & 15);
    const float* __restrict__ b1v = net ? b1g : b1f;
    const float* __restrict__ wl = (net ? W1gv : W1fv) + (size_t)4096 * 1024;
    const float c = b1v[nc] + tarr[step] * wl[nc];
    tileH[eM][(lane >> 4) * 4 + eR][lane & 15] = f2bf(tanhf(ch + c));
  }
  __syncthreads();

  // transpose-read -> HPack half-frag (q = ct>>1, half = ct&1)
  if (wid < 2 && lane < 32) {
    const int mW = wid;
    const int row = lane & 15, kh = lane >> 4;
    const uvec4 v = *(const uvec4*)&tileH[mW][row][kh * 8];
    const int mG2 = mp * 2 + mW;
    const int k8 = (ct & 1) * 2 + kh;
    *(uvec4*)(HPack + ((size_t)((net * 4 + mG2) * 32 + (ct >> 1))) * 512
              + (k8 * 16 + row) * 8) = v;
  }
}

// ---------------- G2: C = H @ W2 (f,g) -> SDE update -> A, APack, out ----------------
// grid 256 = mp(2) x ct32(128). 8 waves = ks(2) x net(2) x m(2). Wave: 16x32,
// K=512 half, 16 chunk-stream (1 H + 2 W2 streams), no barriers in K-loop.
__global__ __launch_bounds__(512, 2) void g2_update(
    const u16* __restrict__ HPack, const u16* __restrict__ W2P,
    const float* __restrict__ b2f, const float* __restrict__ b2g,
    float* __restrict__ A, u16* __restrict__ APack,
    const float* __restrict__ dwstep, float* __restrict__ out,
    const float* __restrict__ tarr, int step) {
  __shared__ f32x4 ex[8][64][2];
  __shared__ __align__(16) u16 tileA[2][16][32];
  const int bid = blockIdx.x, tix = threadIdx.x;
  const int wid = tix >> 6, lane = tix & 63;
  const int mp = bid >> 7, ct32 = bid & 127;
  const int ks = wid >> 2, net = (wid >> 1) & 1, m = wid & 1;
  const int mG = mp * 2 + m;
  const u16* ph = HPack + ((size_t)((net * 4 + mG) * 32 + ks * 16)) * 512 + lane * 8;
  const u16* pw0 = W2P + ((size_t)((net * 256 + ct32 * 2 + 0) * 32 + ks * 16)) * 512 + lane * 8;
  const u16* pw1 = W2P + ((size_t)((net * 256 + ct32 * 2 + 1) * 32 + ks * 16)) * 512 + lane * 8;

  bf16x8 hv[8], w0[8], w1[8];
  #pragma unroll
  for (int d = 0; d < 8; ++d) {
    hv[d] = *(const bf16x8*)(ph + d * 512);
    w0[d] = *(const bf16x8*)(pw0 + d * 512);
    w1[d] = *(const bf16x8*)(pw1 + d * 512);
  }
  f32x4 a0 = {0.f, 0.f, 0.f, 0.f}, a1 = {0.f, 0.f, 0.f, 0.f};
  #pragma unroll
  for (int j = 0; j < 16; ++j) {
    const int s = j & 7;
    a0 = MFMA(hv[s], w0[s], a0);
    a1 = MFMA(hv[s], w1[s], a1);
    if (j + 8 < 16) {
      hv[s] = *(const bf16x8*)(ph + (j + 8) * 512);
      w0[s] = *(const bf16x8*)(pw0 + (j + 8) * 512);
      w1[s] = *(const bf16x8*)(pw1 + (j + 8) * 512);
    }
  }
  ex[wid][lane][0] = a0;
  ex[wid][lane][1] = a1;
  __syncthreads();

  // distributed epilogue: wave -> (eM = wid&1, eCf = (wid>>1)&1, eRh = wid>>2)
  {
    const float dt = tarr[1] - tarr[0];
    const int eM = wid & 1, eCf = (wid >> 1) & 1, eRh = wid >> 2;
    const f32x4 cfv = ex[eM][lane][eCf] + ex[4 + eM][lane][eCf];       // net=0: ks0+ks1
    const f32x4 cgv = ex[2 + eM][lane][eCf] + ex[6 + eM][lane][eCf];   // net=1
    const int nc = ct32 * 32 + eCf * 16 + (lane & 15);
    const float bfv = b2f[nc], bgv = b2g[nc];
    #pragma unroll
    for (int ri = 0; ri < 2; ++ri) {
      const int r = eRh * 2 + ri;
      const int row = mp * 32 + eM * 16 + (lane >> 4) * 4 + r;
      const float drift = cfv[r] + bfv;
      const float graw = cgv[r] + bgv;
      const float diff = fmaxf(graw, 0.0f) + log1pf(expf(-fabsf(graw)));  // softplus
      const int e = row * 4096 + nc;
      const float anew = A[e] + drift * dt + diff * dwstep[e];
      A[e] = anew;
      tileA[eM][(lane >> 4) * 4 + r][eCf * 16 + (lane & 15)] = f2bf(anew);
      const float sig = (nc % 65 == 0) ? 0.0f : 1.0f / (1.0f + expf(-anew));
      #pragma unroll
      for (int s = 0; s < 4; ++s)
        out[((size_t)(s * 64 + step + 1) * 64 + row) * 4096 + nc] = sig;
    }
  }
  __syncthreads();

  // transpose-read -> APack frag (q = ct32)
  if (wid < 2) {
    const int mW = wid;
    const int row = lane & 15, kq = lane >> 4;
    const uvec4 v = *(const uvec4*)&tileA[mW][row][kq * 8];
    *(uvec4*)(APack + ((size_t)((mp * 2 + mW) * 128 + ct32)) * 512 + lane * 8) = v;
  }
}

// ---------------- launch ----------------
extern "C" void kernel_launch(void* const* d_in, const int* in_sizes, int n_in,
                              void* d_out, int out_size, void* d_ws, size_t ws_size,
                              hipStream_t stream) {
  const float* A0 = (const float*)d_in[0];
  const float* tarr = (const float*)d_in[1];
  const float* W1f = (const float*)d_in[2];
  const float* b1f = (const float*)d_in[3];
  const float* W2f = (const float*)d_in[4];
  const float* b2f = (const float*)d_in[5];
  const float* W1g = (const float*)d_in[6];
  const float* b1g = (const float*)d_in[7];
  const float* W2g = (const float*)d_in[8];
  const float* b2g = (const float*)d_in[9];
  float* out = (float*)d_out;
  char* ws = (char*)d_ws;
  const size_t MB = 1024 * 1024;
  u16* W1P   = (u16*)(ws + 0 * MB);        // 16 MB packed frags
  u16* W2P   = (u16*)(ws + 16 * MB);       // 16 MB
  u16* APack = (u16*)(ws + 32 * MB);       // 512 KB
  u16* HPack = (u16*)(ws + 33 * MB);       // 256 KB
  float* A   = (float*)(ws + 34 * MB);     // 1 MB f32 state
  float* dwfb  = (float*)(ws + 35 * MB);   // 1 MB fallback
  float* dwall = (float*)(ws + 36 * MB);   // 63 MB pregen
  const bool pre = ws_size >= (size_t)100 * MB;

  s1_frag<<<dim3(8192), 256, 0, stream>>>(W1f, W1g, W2f, W2g, W1P, W2P);
  s2_init<<<dim3(1024), 256, 0, stream>>>(A0, A, APack, out);
  if (pre) dw_gen<<<dim3(63 * 32), 256, 0, stream>>>(tarr, dwall, -1);
  for (int i = 0; i < 63; ++i) {
    if (!pre) dw_gen<<<dim3(32), 256, 0, stream>>>(tarr, dwfb, i);
    g1_hidden<<<dim3(256), 512, 0, stream>>>(APack, W1P, HPack, b1f, b1g,
                                             W1f, W1g, tarr, i);
    const float* dwstep = pre ? (dwall + (size_t)i * 262144) : dwfb;
    g2_update<<<dim3(256), 512, 0, stream>>>(HPack, W2P, b2f, b2g,
                                             A, APack, dwstep, out, tarr, i);
  }
}